// Round 3
// baseline (263.765 us; speedup 1.0000x reference)
//
#include <hip/hip_runtime.h>
#include <hip/hip_bf16.h>

typedef unsigned short u16;
typedef unsigned int u32;
typedef __attribute__((ext_vector_type(8))) __bf16 bf16x8;
typedef __attribute__((ext_vector_type(4))) float f32x4;
typedef __attribute__((ext_vector_type(16))) float f32x16;

constexpr int Bz = 2, Sq = 2048, Dm = 1024, Hn = 16, DK = 64;

__device__ __forceinline__ u16 f2bf(float f) {
    u32 u = __builtin_bit_cast(u32, f);
    return (u16)((u + 0x7FFFu + ((u >> 16) & 1u)) >> 16);   // RNE
}

__device__ __forceinline__ u32 pack_bf16(float a, float b) {
#if __has_builtin(__builtin_amdgcn_cvt_pk_bf16_f32)
    return __builtin_bit_cast(u32, __builtin_amdgcn_cvt_pk_bf16_f32(a, b));
#else
    return (u32)f2bf(a) | ((u32)f2bf(b) << 16);
#endif
}

__device__ __forceinline__ bf16x8 lds_frag(const u16* p) {
    return __builtin_bit_cast(bf16x8, *(const uint4*)p);
}

// async global->LDS, 16B per lane; LDS dest = wave-uniform base + lane*16
__device__ __forceinline__ void gll16(const u16* g, u16* l) {
    __builtin_amdgcn_global_load_lds(
        (const __attribute__((address_space(1))) void*)g,
        (__attribute__((address_space(3))) void*)l, 16, 0, 0);
}

// ---------------------------------------------------------------------------
// Kernel 0: cast q,k,v fp32 -> bf16
// ---------------------------------------------------------------------------
__global__ __launch_bounds__(256) void mha_cast(
    const float* __restrict__ q, const float* __restrict__ k,
    const float* __restrict__ v, u16* __restrict__ dst_base)
{
    const int z = blockIdx.z;
    const float* s = (z == 0) ? q : (z == 1) ? k : v;
    u16* d = dst_base + (size_t)z * 4 * 1024 * 1024;
    size_t i = ((size_t)blockIdx.x * 256 + threadIdx.x) * 8;
    float4 a = *(const float4*)(s + i);
    float4 b = *(const float4*)(s + i + 4);
    *(uint4*)(d + i) = make_uint4(pack_bf16(a.x, a.y), pack_bf16(a.z, a.w),
                                  pack_bf16(b.x, b.y), pack_bf16(b.z, b.w));
}

// ---------------------------------------------------------------------------
// Kernel 1: transpose + cast the 4 weight matrices -> Wt [N,K] bf16
// ---------------------------------------------------------------------------
__global__ __launch_bounds__(256) void mha_transpose_w(
    const float* __restrict__ w0, const float* __restrict__ w1,
    const float* __restrict__ w2, const float* __restrict__ w3,
    u16* __restrict__ dst_base)
{
    __shared__ float tile[32][33];
    const int z = blockIdx.z;
    const float* src = (z == 0) ? w0 : (z == 1) ? w1 : (z == 2) ? w2 : w3;
    u16* d = dst_base + (size_t)z * Dm * Dm;
    const int bx = blockIdx.x * 32, by = blockIdx.y * 32;
    const int tx = threadIdx.x, ty = threadIdx.y;   // 32 x 8
#pragma unroll
    for (int i = 0; i < 4; i++) {
        int kk = ty + i * 8;
        tile[kk][tx] = src[(size_t)(by + kk) * Dm + bx + tx];
    }
    __syncthreads();
#pragma unroll
    for (int i = 0; i < 4; i++) {
        int nn = ty + i * 8;
        d[(size_t)(bx + nn) * Dm + by + tx] = f2bf(tile[tx][nn]);
    }
}

// ---------------------------------------------------------------------------
// m97-style GEMM core: C[128x128] = A[128xK] @ B[128xK]^T, K=1024, BK=32
// ---------------------------------------------------------------------------
__device__ __forceinline__ void gemm_core_dma(
    const u16* __restrict__ Ab, const u16* __restrict__ Bb,
    u16* As, u16* Bs, f32x4 (&acc)[4][4])
{
    const int tid = threadIdx.x, lane = tid & 63;
    const int wm = (tid >> 7) & 1, wn = (tid >> 6) & 1;
    const int frow = lane & 15, quad = lane >> 4;
    const int r0 = tid >> 2,         c0 = tid & 3;
    const int r1 = (tid + 256) >> 2, c1 = tid & 3;

#pragma unroll
    for (int mi = 0; mi < 4; mi++)
#pragma unroll
        for (int ni = 0; ni < 4; ni++) acc[mi][ni] = (f32x4){0.f, 0.f, 0.f, 0.f};

    for (int k0 = 0; k0 < 1024; k0 += 32) {
        gll16(Ab + (size_t)r0 * 1024 + k0 + c0 * 8, &As[tid * 8]);
        gll16(Ab + (size_t)r1 * 1024 + k0 + c1 * 8, &As[(tid + 256) * 8]);
        gll16(Bb + (size_t)r0 * 1024 + k0 + c0 * 8, &Bs[tid * 8]);
        gll16(Bb + (size_t)r1 * 1024 + k0 + c1 * 8, &Bs[(tid + 256) * 8]);
        __syncthreads();
        bf16x8 af[4], bfr[4];
#pragma unroll
        for (int mi = 0; mi < 4; mi++)
            af[mi] = lds_frag(&As[(wm * 64 + mi * 16 + frow) * 32 + quad * 8]);
#pragma unroll
        for (int ni = 0; ni < 4; ni++)
            bfr[ni] = lds_frag(&Bs[(wn * 64 + ni * 16 + frow) * 32 + quad * 8]);
#pragma unroll
        for (int mi = 0; mi < 4; mi++)
#pragma unroll
            for (int ni = 0; ni < 4; ni++)
                acc[mi][ni] = __builtin_amdgcn_mfma_f32_16x16x32_bf16(
                    af[mi], bfr[ni], acc[mi][ni], 0, 0, 0);
        __syncthreads();
    }
}

// ---------------------------------------------------------------------------
// Kernel 2: QKV projections. z=0: Q->[B,H,S,DK]; z=1: K->[B,H,S,DK];
// z=2: SWAPPED operands -> computes V'^T directly, coalesced [B,H,DK,S] write.
// ---------------------------------------------------------------------------
__global__ __launch_bounds__(256) void mha_proj_qkv(
    const u16* __restrict__ Qb, const u16* __restrict__ Kb, const u16* __restrict__ Vb,
    const u16* __restrict__ Wqt, const u16* __restrict__ Wkt, const u16* __restrict__ Wvt,
    const float* __restrict__ bq, const float* __restrict__ bk, const float* __restrict__ bv,
    u16* __restrict__ Qh, u16* __restrict__ Kh, u16* __restrict__ Vt)
{
    __shared__ __align__(16) u16 As[128 * 32];
    __shared__ __align__(16) u16 Bs[128 * 32];
    const int z = blockIdx.z, bx = blockIdx.x;
    const u16* Ab; const u16* Bb; const float* bias;
    int m0, n0;
    if (z < 2) {
        m0 = (bx >> 3) * 128; n0 = (bx & 7) * 128;
        Ab = ((z == 0) ? Qb : Kb) + (size_t)m0 * Dm;
        Bb = ((z == 0) ? Wqt : Wkt) + (size_t)n0 * Dm;
        bias = (z == 0) ? bq : bk;
    } else {
        m0 = (bx & 7) * 128; n0 = (bx >> 3) * 128;
        Ab = Wvt + (size_t)m0 * Dm;
        Bb = Vb + (size_t)n0 * Dm;
        bias = bv;
    }

    f32x4 acc[4][4];
    gemm_core_dma(Ab, Bb, As, Bs, acc);

    const int tid = threadIdx.x, lane = tid & 63;
    const int wm = (tid >> 7) & 1, wn = (tid >> 6) & 1;
    const int frow = lane & 15, quad = lane >> 4;
    u16* dstq = (z == 0) ? Qh : Kh;
#pragma unroll
    for (int mi = 0; mi < 4; mi++)
#pragma unroll
        for (int ni = 0; ni < 4; ni++)
#pragma unroll
            for (int r = 0; r < 4; r++) {
                int i = m0 + wm * 64 + mi * 16 + quad * 4 + r;   // row
                int j = n0 + wn * 64 + ni * 16 + frow;           // col
                if (z < 2) {
                    float val = acc[mi][ni][r] + bias[j];
                    int b = i >> 11, s = i & (Sq - 1);
                    int h = j >> 6, dk = j & (DK - 1);
                    dstq[((size_t)(b * Hn + h) * Sq + s) * DK + dk] = f2bf(val);
                } else {
                    float val = acc[mi][ni][r] + bias[i];        // bias on row now
                    int h = i >> 6, dk = i & (DK - 1);
                    int b = j >> 11, s = j & (Sq - 1);
                    Vt[((size_t)(b * Hn + h) * DK + dk) * Sq + s] = f2bf(val);
                }
            }
}

// ---------------------------------------------------------------------------
// Kernel 3: flash attention, no-max exp2 softmax, intra-block split-K.
// 512 threads = 8 waves = 4 q-slices (32 q) x 2 key-parities (64-key halves
// of a 128-key tile). Partials combine linearly at the end (no max shift).
// P slices alias the dead Q staging region.
// ---------------------------------------------------------------------------
__global__ __launch_bounds__(512, 4) void mha_attn(
    const u16* __restrict__ Qh, const u16* __restrict__ Kh, const u16* __restrict__ Vt,
    const int* __restrict__ mask, u16* __restrict__ X)
{
    const int b = blockIdx.z, hh = blockIdx.y, q0 = blockIdx.x * 128;
    const int tid = threadIdx.x, lane = tid & 63, w = tid >> 6;
    const int wq = w & 3, p = w >> 2;           // q-slice, key-parity
    const int qc = lane & 31, half = lane >> 5, sw = qc & 7;
    constexpr float C2 = 0.125f * 1.44269504f;  // 1/sqrt(DK) * log2(e)

    __shared__ __align__(16) u16 PQ[16384];     // 32 KB: Q staging, then P slices, then f32 combine
    __shared__ __align__(16) u16 Ks[128 * 64];  // 16 KB: key-pair tile [key][dk]
    __shared__ __align__(16) u16 Vts[64 * 128]; // 16 KB: V-pair tile [d][key]
    __shared__ float mskp[128];
    __shared__ float lcomb[256];

    const size_t bh = (size_t)(b * Hn + hh);
    const u16* Qp = Qh + bh * Sq * DK;
    const u16* Kp = Kh + bh * Sq * DK;
    const u16* Vp = Vt + bh * DK * Sq;
    u16* Pw = &PQ[w * 2048];                    // 4 KB wave-private P slice

    // ---- stage Q [128][64], chunk-swizzled ----
#pragma unroll
    for (int i = 0; i < 2; i++) {
        int id = tid + i * 512, row = id >> 3, cl = id & 7;
        gll16(Qp + (size_t)(q0 + row) * DK + (cl ^ (row & 7)) * 8, &PQ[id * 8]);
    }
    __syncthreads();
    bf16x8 qf[4];
    {
        int row = wq * 32 + qc;
#pragma unroll
        for (int kc = 0; kc < 4; kc++)
            qf[kc] = lds_frag(&PQ[row * 64 + ((kc * 2 + half) ^ (row & 7)) * 8]);
    }
    // first in-loop barrier guarantees all qf reads drained before P overwrites PQ

    float l_l = 0.f;
    f32x16 o0, o1;
#pragma unroll
    for (int i = 0; i < 16; i++) { o0[i] = 0.f; o1[i] = 0.f; }

    for (int k0 = 0; k0 < Sq; k0 += 128) {
        // ---- stage K pair [128 keys][64 dk], V pair [64 d][128 keys], mask ----
#pragma unroll
        for (int i = 0; i < 2; i++) {
            int id = tid + i * 512;
            {
                int row = id >> 3, cl = id & 7;
                gll16(Kp + (size_t)(k0 + row) * DK + (cl ^ (row & 7)) * 8, &Ks[id * 8]);
            }
            {
                int row = id >> 4, cl = id & 15;
                int lg = (cl & 8) | ((cl & 7) ^ (row & 7));
                gll16(Vp + (size_t)row * Sq + k0 + lg * 8, &Vts[id * 8]);
            }
        }
        if (tid < 128)
            mskp[tid] = (mask[b * Sq + k0 + tid] != 0) ? -1.44269504e10f : 0.f;
        __syncthreads();

        // ---- S^T = K Q^T on this wave's 64-key half ----
        f32x16 sT0, sT1;
#pragma unroll
        for (int i = 0; i < 16; i++) { sT0[i] = 0.f; sT1[i] = 0.f; }
        const int krow0 = p * 64 + qc, krow1 = p * 64 + 32 + qc;
#pragma unroll
        for (int kc = 0; kc < 4; kc++) {
            int cs = ((kc * 2 + half) ^ sw) * 8;
            bf16x8 ka0 = lds_frag(&Ks[krow0 * 64 + cs]);
            bf16x8 ka1 = lds_frag(&Ks[krow1 * 64 + cs]);
            sT0 = __builtin_amdgcn_mfma_f32_32x32x16_bf16(ka0, qf[kc], sT0, 0, 0, 0);
            sT1 = __builtin_amdgcn_mfma_f32_32x32x16_bf16(ka1, qf[kc], sT1, 0, 0, 0);
        }

        // ---- no-max softmax: t = exp2(s*C2 + maskbias); accumulate l ----
        float t0[16], t1[16], rs = 0.f;
        const float* mb = &mskp[p * 64];
#pragma unroll
        for (int g = 0; g < 4; g++) {
            float4 m0v = *(const float4*)&mb[8 * g + 4 * half];
            float4 m1v = *(const float4*)&mb[32 + 8 * g + 4 * half];
#pragma unroll
            for (int r = 0; r < 4; r++) {
                float b0 = (r == 0) ? m0v.x : (r == 1) ? m0v.y : (r == 2) ? m0v.z : m0v.w;
                float b1 = (r == 0) ? m1v.x : (r == 1) ? m1v.y : (r == 2) ? m1v.z : m1v.w;
                float a = __builtin_amdgcn_exp2f(fmaf(sT0[g * 4 + r], C2, b0));
                float c = __builtin_amdgcn_exp2f(fmaf(sT1[g * 4 + r], C2, b1));
                t0[g * 4 + r] = a; t1[g * 4 + r] = c; rs += a + c;
            }
        }
        l_l += rs;

        // ---- P -> wave-private LDS [32 q][64 keys], chunk-swizzled ----
#pragma unroll
        for (int g = 0; g < 4; g++) {
            *(uint2*)&Pw[qc * 64 + ((g ^ sw) * 8) + 4 * half] =
                make_uint2(pack_bf16(t0[g * 4 + 0], t0[g * 4 + 1]),
                           pack_bf16(t0[g * 4 + 2], t0[g * 4 + 3]));
            *(uint2*)&Pw[qc * 64 + (((4 + g) ^ sw) * 8) + 4 * half] =
                make_uint2(pack_bf16(t1[g * 4 + 0], t1[g * 4 + 1]),
                           pack_bf16(t1[g * 4 + 2], t1[g * 4 + 3]));
        }

        // ---- O^T += V P^T on this wave's key half ----
#pragma unroll
        for (int kc = 0; kc < 4; kc++) {
            bf16x8 pf = lds_frag(&Pw[qc * 64 + ((kc * 2 + half) ^ sw) * 8]);
            int vc = (p * 8 + ((kc * 2 + half) ^ sw)) * 8;
            bf16x8 va0 = lds_frag(&Vts[qc * 128 + vc]);
            bf16x8 va1 = lds_frag(&Vts[(32 + qc) * 128 + vc]);
            o0 = __builtin_amdgcn_mfma_f32_32x32x16_bf16(va0, pf, o0, 0, 0, 0);
            o1 = __builtin_amdgcn_mfma_f32_32x32x16_bf16(va1, pf, o1, 0, 0, 0);
        }
        __syncthreads();
    }

    // ---- combine the two key-parity partials (linear: no max shift) ----
    l_l += __shfl_xor(l_l, 32);
    float* fc = (float*)PQ + wq * 2048;   // 8 KB per q-slice: [32 regs][64 lanes]
    if (p == 1) {
#pragma unroll
        for (int r = 0; r < 16; r++) fc[r * 64 + lane] = o0[r];
#pragma unroll
        for (int r = 0; r < 16; r++) fc[(16 + r) * 64 + lane] = o1[r];
        lcomb[wq * 64 + lane] = l_l;
    }
    __syncthreads();
    if (p == 0) {
        float lt = l_l + lcomb[wq * 64 + lane];
        float inv = 1.0f / lt;
#pragma unroll
        for (int r = 0; r < 16; r++) o0[r] += fc[r * 64 + lane];
#pragma unroll
        for (int r = 0; r < 16; r++) o1[r] += fc[(16 + r) * 64 + lane];
        const int qg = q0 + wq * 32 + qc;
        u16* Xp = X + (size_t)(b * Sq + qg) * Dm + hh * DK;
#pragma unroll
        for (int g = 0; g < 4; g++) {
            *(uint2*)&Xp[8 * g + 4 * half] =
                make_uint2(pack_bf16(o0[g * 4 + 0] * inv, o0[g * 4 + 1] * inv),
                           pack_bf16(o0[g * 4 + 2] * inv, o0[g * 4 + 3] * inv));
            *(uint2*)&Xp[32 + 8 * g + 4 * half] =
                make_uint2(pack_bf16(o1[g * 4 + 0] * inv, o1[g * 4 + 1] * inv),
                           pack_bf16(o1[g * 4 + 2] * inv, o1[g * 4 + 3] * inv));
        }
    }
}

// ---------------------------------------------------------------------------
// Kernel 4: out = X @ Wo + bo (fp32 output)
// ---------------------------------------------------------------------------
__global__ __launch_bounds__(256) void mha_oproj(
    const u16* __restrict__ X, const u16* __restrict__ Wot,
    const float* __restrict__ bo, float* __restrict__ out)
{
    __shared__ __align__(16) u16 As[128 * 32];
    __shared__ __align__(16) u16 Bs[128 * 32];
    const int m0 = blockIdx.y * 128, n0 = blockIdx.x * 128;
    f32x4 acc[4][4];
    gemm_core_dma(X + (size_t)m0 * Dm, Wot + (size_t)n0 * Dm, As, Bs, acc);
    const int tid = threadIdx.x, lane = tid & 63;
    const int wm = (tid >> 7) & 1, wn = (tid >> 6) & 1;
    const int frow = lane & 15, quad = lane >> 4;
#pragma unroll
    for (int mi = 0; mi < 4; mi++)
#pragma unroll
        for (int ni = 0; ni < 4; ni++)
#pragma unroll
            for (int r = 0; r < 4; r++) {
                int m = m0 + wm * 64 + mi * 16 + quad * 4 + r;
                int n = n0 + wn * 64 + ni * 16 + frow;
                out[(size_t)m * Dm + n] = acc[mi][ni][r] + bo[n];
            }
}

// ---------------------------------------------------------------------------
extern "C" void kernel_launch(void* const* d_in, const int* in_sizes, int n_in,
                              void* d_out, int out_size, void* d_ws, size_t ws_size,
                              hipStream_t stream)
{
    const float* qin  = (const float*)d_in[0];
    const float* kin  = (const float*)d_in[1];
    const float* vin  = (const float*)d_in[2];
    const int*   mask = (const int*)d_in[3];
    const float* Wq   = (const float*)d_in[4];
    const float* bq   = (const float*)d_in[5];
    const float* Wk   = (const float*)d_in[6];
    const float* bk   = (const float*)d_in[7];
    const float* Wv   = (const float*)d_in[8];
    const float* bv   = (const float*)d_in[9];
    const float* Wo   = (const float*)d_in[10];
    const float* bo   = (const float*)d_in[11];
    float* out = (float*)d_out;

    u16* ws = (u16*)d_ws;
    const size_t MW = (size_t)Dm * Dm;
    const size_t MT = (size_t)Bz * Sq * Dm;
    u16* Wqt = ws;
    u16* Wkt = ws + MW;
    u16* Wvt = ws + 2 * MW;
    u16* Wot = ws + 3 * MW;
    u16* Qb  = ws + 4 * MW;
    u16* Kb  = Qb + MT;
    u16* Vb  = Kb + MT;
    u16* Qh  = Vb + MT;
    u16* Kh  = Qh + MT;
    u16* Vt  = Kh + MT;
    u16* X   = Qb;                 // Qb dead after proj

    hipLaunchKernelGGL(mha_cast, dim3(2048, 1, 3), dim3(256), 0, stream,
                       qin, kin, vin, Qb);
    hipLaunchKernelGGL(mha_transpose_w, dim3(32, 32, 4), dim3(32, 8), 0, stream,
                       Wq, Wk, Wv, Wo, Wqt);
    hipLaunchKernelGGL(mha_proj_qkv, dim3(256, 1, 3), dim3(256), 0, stream,
                       Qb, Kb, Vb, Wqt, Wkt, Wvt, bq, bk, bv, Qh, Kh, Vt);
    hipLaunchKernelGGL(mha_attn, dim3(16, 16, 2), dim3(512), 0, stream,
                       Qh, Kh, Vt, mask, X);
    hipLaunchKernelGGL(mha_oproj, dim3(8, 32), dim3(256), 0, stream,
                       X, Wot, bo, out);
}